// Round 12
// baseline (167.657 us; speedup 1.0000x reference)
//
#include <hip/hip_runtime.h>
#include <hip/hip_bf16.h>

#define H 128
#define ND 4096
#define CH 8      // waves (group-chunks) per drug
#define MAXG 128  // gl2 slots per drug (observed max ~77; 128 = 11 sigma)
#define ZDW (2 * ND + ND * H)   // dwords to zero: dlen | gcnt | dsum

__device__ __forceinline__ float lof(unsigned u) { return __uint_as_float(u << 16); }
__device__ __forceinline__ float hif(unsigned u) { return __uint_as_float(u & 0xffff0000u); }

// K1: psexp[p] = exp(ph[p].w_attn)  AND  phb[p] = bf16(ph[p]).
// Two rows per wave (32 lanes x float4 per row), one pass over the table.
// Also zeroes the accumulator region (dlen|gcnt|dsum) -- no separate memset.
__global__ void k_pscore_cvt(const float* __restrict__ ph,
                             const float* __restrict__ w_attn,
                             float* __restrict__ psexp,
                             __hip_bfloat16* __restrict__ phb,
                             int* __restrict__ zbase, int NP) {
    int gt = blockIdx.x * blockDim.x + threadIdx.x;
    if (gt < ZDW) zbase[gt] = 0;
    int lane = threadIdx.x & 63;
    int half = lane >> 5;
    int l32  = lane & 31;
    int wid  = gt >> 6;
    int row  = wid * 2 + half;
    if (row >= NP) return;
    float4 wa = *(const float4*)(w_attn + 4 * l32);
    float4 v  = *(const float4*)(ph + (size_t)row * H + 4 * l32);
    __hip_bfloat16 b0 = __float2bfloat16(v.x);
    __hip_bfloat16 b1 = __float2bfloat16(v.y);
    __hip_bfloat16 b2 = __float2bfloat16(v.z);
    __hip_bfloat16 b3 = __float2bfloat16(v.w);
    ushort4 pk;
    pk.x = *(unsigned short*)&b0; pk.y = *(unsigned short*)&b1;
    pk.z = *(unsigned short*)&b2; pk.w = *(unsigned short*)&b3;
    *(ushort4*)(phb + (size_t)row * H + 4 * l32) = pk;
    float d = v.x * wa.x + v.y * wa.y + v.z * wa.z + v.w * wa.w;
    #pragma unroll
    for (int off = 16; off >= 1; off >>= 1) d += __shfl_xor(d, off, 64);
    if (l32 == 0) psexp[row] = __expf(d);   // raw exp: scores ~N(0,1), f32-safe
}

// K_prep: boundary threads (group start, sorted gid) walk their group's
// extent; reserve a contiguous in-drug range (dlen atomic) and a group slot
// (gcnt atomic). gl2 slot = {inoff, len} (self-describing, order-free);
// grec[g] = {start, d<<20|inoff} for the scatter pass.
__global__ void k_prep(const int* __restrict__ gid,
                       const int* __restrict__ g2d,
                       int* __restrict__ dlen, int* __restrict__ gcnt,
                       int2* __restrict__ gl2, int2* __restrict__ grec, int E) {
    int t = blockIdx.x * blockDim.x + threadIdx.x;
    if (t >= E) return;
    int g = gid[t];
    if (t == 0 || gid[t - 1] != g) {
        int end = t + 1;
        while (end < E && gid[end] == g) ++end;
        int len = end - t;
        int d = g2d[g];
        int inoff = atomicAdd(&dlen[d], len);
        int slot  = atomicAdd(&gcnt[d], 1);
        if (slot < MAXG) gl2[d * MAXG + slot] = make_int2(inoff, len);
        grec[g] = make_int2(t, (int)(((unsigned)d << 20) | (unsigned)inoff));
    }
}

// K_scan: exclusive prefix over dlen[ND] -> doff. ND = 4096 = 1024 x 4.
__global__ void k_scan(const int* __restrict__ dlen, int* __restrict__ doff) {
    __shared__ int wsum[16];
    __shared__ int wpre[16];
    int t = threadIdx.x;
    int a0 = dlen[4 * t + 0], a1 = dlen[4 * t + 1];
    int a2 = dlen[4 * t + 2], a3 = dlen[4 * t + 3];
    int tot = a0 + a1 + a2 + a3;
    int lane = t & 63, w = t >> 6;
    int x = tot;
    #pragma unroll
    for (int d = 1; d < 64; d <<= 1) {
        int y = __shfl_up(x, d, 64);
        if (lane >= d) x += y;
    }
    if (lane == 63) wsum[w] = x;
    __syncthreads();
    if (t == 0) {
        int acc = 0;
        #pragma unroll
        for (int i = 0; i < 16; ++i) { wpre[i] = acc; acc += wsum[i]; }
    }
    __syncthreads();
    int excl = wpre[w] + x - tot;
    doff[4 * t + 0] = excl;
    doff[4 * t + 1] = excl + a0;
    doff[4 * t + 2] = excl + a0 + a1;
    doff[4 * t + 3] = excl + a0 + a1 + a2;
}

// K_scatter: drug-major entry stream. pw[pos] = prot_idx | bf16(weight)<<16.
// Consecutive t in a group -> consecutive pos: ~coalesced writes. grec is a
// broadcast load within a group; psexp gather is 200KB L2-resident.
__global__ void k_scatter(const int* __restrict__ gid,
                          const int* __restrict__ prot_idx,
                          const float* __restrict__ psexp,
                          const int2* __restrict__ grec,
                          const int* __restrict__ doff,
                          unsigned* __restrict__ pw, int E) {
    int t = blockIdx.x * blockDim.x + threadIdx.x;
    if (t >= E) return;
    int g = gid[t];
    int2 rc = grec[g];
    unsigned pk = (unsigned)rc.y;
    int d = pk >> 20;
    int inoff = pk & 0xFFFFF;
    int pos = doff[d] + inoff + (t - rc.x);
    int p = prot_idx[t];
    __hip_bfloat16 hb = __float2bfloat16(psexp[p]);
    pw[pos] = (unsigned)p | ((unsigned)*(unsigned short*)&hb << 16);
}

// K_fused_drug: one wave per (drug, chunk). lane = (slot=lane>>4, sub=lane&15).
// Each lane loads uint4 = 8 bf16 dims of entry slot+4j: one gather fetches
// FOUR complete 256B rows; 16 entries/iter = 4 independent gathers + ONE
// contiguous pw stream load (idx+weight fused in 4B). Chain per group is now
// gl2(L1) -> pw stream(L1) -> shfl -> gather: single high-latency hop.
// Per-group denom: 2-step shfl_xor across slots. Flush once per wave via
// per-wave LDS transpose + 2 contiguous full-wave atomic instructions.
__global__ void k_fused_drug(const __hip_bfloat16* __restrict__ phb,
                             const unsigned* __restrict__ pw,
                             const int2* __restrict__ gl2,
                             const int* __restrict__ gcnt,
                             const int* __restrict__ doff,
                             float* __restrict__ dsum) {
    __shared__ float xbuf[4][H];
    int w    = threadIdx.x >> 6;
    int lane = threadIdx.x & 63;
    int slot = lane >> 4;
    int sub  = lane & 15;
    int wid  = (blockIdx.x * blockDim.x + threadIdx.x) >> 6;
    wid = __builtin_amdgcn_readfirstlane(wid);   // wave-uniform -> SGPR
    int d = wid >> 3;          // wid / CH
    int c = wid & (CH - 1);
    if (d >= ND) return;
    int gn = gcnt[d];
    if (gn > MAXG) gn = MAXG;
    int dbase = doff[d];
    const int2* gl = gl2 + d * MAXG;
    const __hip_bfloat16* base = phb + sub * 8;
    float ax[8];
    #pragma unroll
    for (int k = 0; k < 8; ++k) ax[k] = 0.f;
    for (int i = c; i < gn; i += CH) {
        int2 A = gl[i];
        int off0 = dbase + A.x;
        int len  = A.y;
        float sa = 0.f;
        float gx[8];
        #pragma unroll
        for (int k = 0; k < 8; ++k) gx[k] = 0.f;
        for (int e = 0; e < len; e += 16) {
            int ii = e + sub;                 // lane's probe entry (group-local)
            int ic = min(ii, len - 1);
            unsigned uv = pw[off0 + ic];
            int   pv = (int)(uv & 0xffffu);
            float wv = (ii < len) ? hif(uv) : 0.f;
            int   p0 = __shfl(pv, slot,      16);
            int   p1 = __shfl(pv, slot + 4,  16);
            int   p2 = __shfl(pv, slot + 8,  16);
            int   p3 = __shfl(pv, slot + 12, 16);
            float w0 = __shfl(wv, slot,      16);
            float w1 = __shfl(wv, slot + 4,  16);
            float w2 = __shfl(wv, slot + 8,  16);
            float w3 = __shfl(wv, slot + 12, 16);
            uint4 r0 = *(const uint4*)(base + (size_t)p0 * H);
            uint4 r1 = *(const uint4*)(base + (size_t)p1 * H);
            uint4 r2 = *(const uint4*)(base + (size_t)p2 * H);
            uint4 r3 = *(const uint4*)(base + (size_t)p3 * H);
            sa += (w0 + w1) + (w2 + w3);
            gx[0] += w0 * lof(r0.x) + w1 * lof(r1.x) + w2 * lof(r2.x) + w3 * lof(r3.x);
            gx[1] += w0 * hif(r0.x) + w1 * hif(r1.x) + w2 * hif(r2.x) + w3 * hif(r3.x);
            gx[2] += w0 * lof(r0.y) + w1 * lof(r1.y) + w2 * lof(r2.y) + w3 * lof(r3.y);
            gx[3] += w0 * hif(r0.y) + w1 * hif(r1.y) + w2 * hif(r2.y) + w3 * hif(r3.y);
            gx[4] += w0 * lof(r0.z) + w1 * lof(r1.z) + w2 * lof(r2.z) + w3 * lof(r3.z);
            gx[5] += w0 * hif(r0.z) + w1 * hif(r1.z) + w2 * hif(r2.z) + w3 * hif(r3.z);
            gx[6] += w0 * lof(r0.w) + w1 * lof(r1.w) + w2 * lof(r2.w) + w3 * lof(r3.w);
            gx[7] += w0 * hif(r0.w) + w1 * hif(r1.w) + w2 * hif(r2.w) + w3 * hif(r3.w);
        }
        float st = sa;                        // entries split across slots
        st += __shfl_xor(st, 16, 64);
        st += __shfl_xor(st, 32, 64);
        float inv = 1.0f / st;
        #pragma unroll
        for (int k = 0; k < 8; ++k) ax[k] += gx[k] * inv;
    }
    // reduce across slots; every lane ends with the full sum for its dims
    #pragma unroll
    for (int k = 0; k < 8; ++k) {
        ax[k] += __shfl_xor(ax[k], 16, 64);
        ax[k] += __shfl_xor(ax[k], 32, 64);
    }
    // per-wave LDS transpose (same-wave ds ordering, no barrier needed)
    if (slot == 0) {
        *(float4*)&xbuf[w][8 * sub]     = make_float4(ax[0], ax[1], ax[2], ax[3]);
        *(float4*)&xbuf[w][8 * sub + 4] = make_float4(ax[4], ax[5], ax[6], ax[7]);
    }
    float2 f2 = *(const float2*)&xbuf[w][2 * lane];
    float* dst = dsum + (size_t)d * H + 2 * lane;
    atomicAdd(dst,     f2.x);
    atomicAdd(dst + 1, f2.y);
}

// K4: one block (128 threads) per drug. fingerprint staged in LDS, each
// thread j dots its own w_out row (float4, L2-resident) + bias + ReLU.
// gcnt[d] == number of non-empty groups for drug d.
__global__ void k4_out(const float* __restrict__ dsum,
                       const int* __restrict__ gcnt,
                       const float* __restrict__ w_out,
                       const float* __restrict__ b_out,
                       float* __restrict__ out) {
    __shared__ float fp[H];
    int d = blockIdx.x;
    int j = threadIdx.x;
    int c = gcnt[d];
    float f = 0.f;
    if (c > 0) f = dsum[(size_t)d * H + j] / (float)c;
    fp[j] = f;
    __syncthreads();
    const float4* wrow = (const float4*)(w_out + (size_t)j * H);
    const float4* fvec = (const float4*)fp;
    float acc = 0.f;
    #pragma unroll
    for (int i = 0; i < H / 4; ++i) {
        float4 w4 = wrow[i];
        float4 f4 = fvec[i];
        acc += w4.x * f4.x + w4.y * f4.y + w4.z * f4.z + w4.w * f4.w;
    }
    acc += b_out[j];
    out[(size_t)d * H + j] = fmaxf(acc, 0.f);
}

extern "C" void kernel_launch(void* const* d_in, const int* in_sizes, int n_in,
                              void* d_out, int out_size, void* d_ws, size_t ws_size,
                              hipStream_t stream) {
    const float* protein_h = (const float*)d_in[0];
    const float* w_attn    = (const float*)d_in[1];
    const float* w_out     = (const float*)d_in[2];
    const float* b_out     = (const float*)d_in[3];
    const int*   prot_idx  = (const int*)d_in[4];
    const int*   group_ids = (const int*)d_in[5];
    const int*   g2d       = (const int*)d_in[6];

    const int E  = in_sizes[4];
    const int G  = in_sizes[6];
    const int NP = in_sizes[0] / H;

    // Workspace (~29 MB):
    // phb | psexp | pw | gl2 | grec | doff | [ZERO: dlen gcnt dsum]
    __hip_bfloat16* phb = (__hip_bfloat16*)d_ws;          // NP*H bf16
    float*    psexp = (float*)(phb + (size_t)NP * H);     // NP
    unsigned* pw    = (unsigned*)(psexp + NP);            // E
    int2*     gl2   = (int2*)(pw + E);                    // ND*MAXG
    int2*     grec  = gl2 + (size_t)ND * MAXG;            // G
    int*      doff  = (int*)(grec + G);                   // ND
    int*      dlen  = doff + ND;                          // ND  (zeroed in k1)
    int*      gcnt  = dlen + ND;                          // ND  (zeroed in k1)
    float*    dsum  = (float*)(gcnt + ND);                // ND*H (zeroed in k1)

    // Per-protein exp(logit) + bf16 table + accumulator zeroing.
    int pw_blocks = (NP + 7) / 8;
    k_pscore_cvt<<<pw_blocks, 256, 0, stream>>>(protein_h, w_attn, psexp, phb,
                                                dlen, NP);

    // Group boundaries -> per-drug slot {inoff,len} + scatter records.
    k_prep<<<(E + 255) / 256, 256, 0, stream>>>(group_ids, g2d, dlen, gcnt,
                                                gl2, grec, E);

    // Per-drug base offsets.
    k_scan<<<1, 1024, 0, stream>>>(dlen, doff);

    // Drug-major fused stream: idx | bf16 weight per entry.
    k_scatter<<<(E + 255) / 256, 256, 0, stream>>>(group_ids, prot_idx, psexp,
                                                   grec, doff, pw, E);

    // Drug-major fused pooling: ND*CH waves, 4 waves per block.
    k_fused_drug<<<(ND * CH) / 4, 256, 0, stream>>>(phb, pw, gl2, gcnt, doff,
                                                    dsum);

    // Fingerprint + out_proj + ReLU.
    k4_out<<<ND, H, 0, stream>>>(dsum, gcnt, w_out, b_out, (float*)d_out);
}

// Round 13
// 153.976 us; speedup vs baseline: 1.0889x; 1.0889x over previous
//
#include <hip/hip_runtime.h>
#include <hip/hip_bf16.h>

#define H 128
#define ND 4096
#define CH 8      // waves (group-chunks) per drug
#define MAXG 128  // gl2 slots per drug (observed max ~77; 128 = 11 sigma)
#define ZDW (ND + ND * H)   // dwords to zero: gcnt | dsum

__device__ __forceinline__ float lof(unsigned u) { return __uint_as_float(u << 16); }
__device__ __forceinline__ float hif(unsigned u) { return __uint_as_float(u & 0xffff0000u); }

// Select component `slot` (0..3) of a uniform uint4 -- 3 v_cndmask, replaces
// ds_bpermute broadcast.
__device__ __forceinline__ unsigned sel4(uint4 q, int slot) {
    unsigned a = (slot & 1) ? q.y : q.x;
    unsigned b = (slot & 1) ? q.w : q.z;
    return (slot & 2) ? b : a;
}

// K1: psexp[p] = exp(ph[p].w_attn)  AND  phb[p] = bf16(ph[p]).
// Two rows per wave (32 lanes x float4 per row), one pass over the table.
// Also zeroes the accumulator region (gcnt|dsum) -- no separate memset.
__global__ void k_pscore_cvt(const float* __restrict__ ph,
                             const float* __restrict__ w_attn,
                             float* __restrict__ psexp,
                             __hip_bfloat16* __restrict__ phb,
                             int* __restrict__ zbase, int NP) {
    int gt = blockIdx.x * blockDim.x + threadIdx.x;
    if (gt < ZDW) zbase[gt] = 0;
    int lane = threadIdx.x & 63;
    int half = lane >> 5;
    int l32  = lane & 31;
    int wid  = gt >> 6;
    int row  = wid * 2 + half;
    if (row >= NP) return;
    float4 wa = *(const float4*)(w_attn + 4 * l32);
    float4 v  = *(const float4*)(ph + (size_t)row * H + 4 * l32);
    __hip_bfloat16 b0 = __float2bfloat16(v.x);
    __hip_bfloat16 b1 = __float2bfloat16(v.y);
    __hip_bfloat16 b2 = __float2bfloat16(v.z);
    __hip_bfloat16 b3 = __float2bfloat16(v.w);
    ushort4 pk;
    pk.x = *(unsigned short*)&b0; pk.y = *(unsigned short*)&b1;
    pk.z = *(unsigned short*)&b2; pk.w = *(unsigned short*)&b3;
    *(ushort4*)(phb + (size_t)row * H + 4 * l32) = pk;
    float d = v.x * wa.x + v.y * wa.y + v.z * wa.z + v.w * wa.w;
    #pragma unroll
    for (int off = 16; off >= 1; off >>= 1) d += __shfl_xor(d, off, 64);
    if (l32 == 0) psexp[row] = __expf(d);   // raw exp: scores ~N(0,1), f32-safe
}

// K_prep: per entry t: pw[t] = prot_idx[t] | bf16(exp(score))<<16 (coalesced,
// original order -- group entries are contiguous since gid is sorted).
// Boundary threads walk their group's extent and append {start,len} to the
// owning drug's list. Raw exp is f32-safe and equals the reference's
// max-subtracted softmax after normalization.
__global__ void k_prep(const int* __restrict__ gid,
                       const int* __restrict__ prot_idx,
                       const float* __restrict__ psexp,
                       const int* __restrict__ g2d,
                       int* __restrict__ gcnt, int2* __restrict__ gl2,
                       unsigned* __restrict__ pw, int E) {
    int t = blockIdx.x * blockDim.x + threadIdx.x;
    if (t >= E) return;
    int p = prot_idx[t];
    __hip_bfloat16 hb = __float2bfloat16(psexp[p]);
    pw[t] = (unsigned)p | ((unsigned)*(unsigned short*)&hb << 16);
    int g = gid[t];
    if (t == 0 || gid[t - 1] != g) {
        int end = t + 1;
        while (end < E && gid[end] == g) ++end;
        int d = g2d[g];
        int slot = atomicAdd(&gcnt[d], 1);
        if (slot < MAXG) gl2[d * MAXG + slot] = make_int2(t, end - t);
    }
}

// K_fused_drug: one wave per (drug, chunk). lane = (slot=lane>>4, sub=lane&15).
// All group metadata is wave-uniform: gl2[i] and the 16 pw words load via the
// SCALAR path (s_load, lgkmcnt -- independent of the gather vmcnt pipe);
// lane distribution is 3 v_cndmask (no ds_bpermute on the critical path).
// Each lane gathers uint4 = 8 bf16 dims of entry slot+4j: one instruction
// fetches FOUR complete 256B rows. Quad-level uniform guards skip fully-tail
// gathers (len~10 < 16). Loads grouped before accumulates for vmcnt overlap.
// Per-group denom: 2-step shfl_xor across slots. Flush once per wave via
// per-wave LDS transpose + 2 contiguous full-wave atomic instructions.
__global__ void k_fused_drug(const __hip_bfloat16* __restrict__ phb,
                             const unsigned* __restrict__ pw,
                             const int2* __restrict__ gl2,
                             const int* __restrict__ gcnt,
                             float* __restrict__ dsum) {
    __shared__ float xbuf[4][H];
    int w    = threadIdx.x >> 6;
    int lane = threadIdx.x & 63;
    int slot = lane >> 4;
    int sub  = lane & 15;
    int wid  = (blockIdx.x * blockDim.x + threadIdx.x) >> 6;
    wid = __builtin_amdgcn_readfirstlane(wid);   // wave-uniform -> SGPR
    int d = wid >> 3;          // wid / CH
    int c = wid & (CH - 1);
    if (d >= ND) return;
    int gn = gcnt[d];
    if (gn > MAXG) gn = MAXG;
    const int2* gl = gl2 + d * MAXG;
    const __hip_bfloat16* base = phb + sub * 8;
    float ax[8];
    #pragma unroll
    for (int k = 0; k < 8; ++k) ax[k] = 0.f;
    for (int i = c; i < gn; i += CH) {
        int2 A = gl[i];
        int s0  = __builtin_amdgcn_readfirstlane(A.x);
        int len = __builtin_amdgcn_readfirstlane(A.y);
        float sa = 0.f;
        float gx[8];
        #pragma unroll
        for (int k = 0; k < 8; ++k) gx[k] = 0.f;
        for (int e = 0; e < len; e += 16) {
            const uint4* pp = (const uint4*)(pw + s0 + e);  // uniform -> s_load
            uint4 q[4];
            q[0] = pp[0]; q[1] = pp[1]; q[2] = pp[2]; q[3] = pp[3];
            int rem = len - e;
            int p0 = (int)(q[0].x & 0xffffu);               // scalar fallback row
            float wv[4]; int pv[4];
            #pragma unroll
            for (int j = 0; j < 4; ++j) {
                unsigned uv = sel4(q[j], slot);
                int ii = 4 * j + slot;
                bool valid = ii < rem;
                wv[j] = valid ? hif(uv) : 0.f;
                pv[j] = valid ? (int)(uv & 0xffffu) : p0;
            }
            uint4 rr[4];
            #pragma unroll
            for (int j = 0; j < 4; ++j)
                if (4 * j < rem) rr[j] = *(const uint4*)(base + (size_t)pv[j] * H);
            #pragma unroll
            for (int j = 0; j < 4; ++j)
                if (4 * j < rem) {
                    sa += wv[j];
                    gx[0] += wv[j] * lof(rr[j].x);
                    gx[1] += wv[j] * hif(rr[j].x);
                    gx[2] += wv[j] * lof(rr[j].y);
                    gx[3] += wv[j] * hif(rr[j].y);
                    gx[4] += wv[j] * lof(rr[j].z);
                    gx[5] += wv[j] * hif(rr[j].z);
                    gx[6] += wv[j] * lof(rr[j].w);
                    gx[7] += wv[j] * hif(rr[j].w);
                }
        }
        float st = sa;                        // entries split across slots
        st += __shfl_xor(st, 16, 64);
        st += __shfl_xor(st, 32, 64);
        float inv = 1.0f / st;
        #pragma unroll
        for (int k = 0; k < 8; ++k) ax[k] += gx[k] * inv;
    }
    // reduce across slots; every lane ends with the full sum for its dims
    #pragma unroll
    for (int k = 0; k < 8; ++k) {
        ax[k] += __shfl_xor(ax[k], 16, 64);
        ax[k] += __shfl_xor(ax[k], 32, 64);
    }
    // per-wave LDS transpose (same-wave ds ordering, no barrier needed)
    if (slot == 0) {
        *(float4*)&xbuf[w][8 * sub]     = make_float4(ax[0], ax[1], ax[2], ax[3]);
        *(float4*)&xbuf[w][8 * sub + 4] = make_float4(ax[4], ax[5], ax[6], ax[7]);
    }
    float2 f2 = *(const float2*)&xbuf[w][2 * lane];
    float* dst = dsum + (size_t)d * H + 2 * lane;
    atomicAdd(dst,     f2.x);
    atomicAdd(dst + 1, f2.y);
}

// K4: one block (128 threads) per drug. fingerprint staged in LDS, each
// thread j dots its own w_out row (float4, L2-resident) + bias + ReLU.
// gcnt[d] == number of non-empty groups for drug d.
__global__ void k4_out(const float* __restrict__ dsum,
                       const int* __restrict__ gcnt,
                       const float* __restrict__ w_out,
                       const float* __restrict__ b_out,
                       float* __restrict__ out) {
    __shared__ float fp[H];
    int d = blockIdx.x;
    int j = threadIdx.x;
    int c = gcnt[d];
    float f = 0.f;
    if (c > 0) f = dsum[(size_t)d * H + j] / (float)c;
    fp[j] = f;
    __syncthreads();
    const float4* wrow = (const float4*)(w_out + (size_t)j * H);
    const float4* fvec = (const float4*)fp;
    float acc = 0.f;
    #pragma unroll
    for (int i = 0; i < H / 4; ++i) {
        float4 w4 = wrow[i];
        float4 f4 = fvec[i];
        acc += w4.x * f4.x + w4.y * f4.y + w4.z * f4.z + w4.w * f4.w;
    }
    acc += b_out[j];
    out[(size_t)d * H + j] = fmaxf(acc, 0.f);
}

extern "C" void kernel_launch(void* const* d_in, const int* in_sizes, int n_in,
                              void* d_out, int out_size, void* d_ws, size_t ws_size,
                              hipStream_t stream) {
    const float* protein_h = (const float*)d_in[0];
    const float* w_attn    = (const float*)d_in[1];
    const float* w_out     = (const float*)d_in[2];
    const float* b_out     = (const float*)d_in[3];
    const int*   prot_idx  = (const int*)d_in[4];
    const int*   group_ids = (const int*)d_in[5];
    const int*   g2d       = (const int*)d_in[6];

    const int E  = in_sizes[4];
    const int NP = in_sizes[0] / H;

    // Workspace (~25 MB): phb | psexp | pw(+pad) | gl2 | [ZERO: gcnt dsum]
    __hip_bfloat16* phb = (__hip_bfloat16*)d_ws;          // NP*H bf16
    float*    psexp = (float*)(phb + (size_t)NP * H);     // NP
    unsigned* pw    = (unsigned*)(psexp + NP);            // E + 16 pad
    int2*     gl2   = (int2*)(pw + E + 16);               // ND*MAXG
    int*      gcnt  = (int*)(gl2 + (size_t)ND * MAXG);    // ND  (zeroed in k1)
    float*    dsum  = (float*)(gcnt + ND);                // ND*H (zeroed in k1)

    // Per-protein exp(logit) + bf16 table + accumulator zeroing.
    int pw_blocks = (NP + 7) / 8;
    k_pscore_cvt<<<pw_blocks, 256, 0, stream>>>(protein_h, w_attn, psexp, phb,
                                                gcnt, NP);

    // Fused per-entry stream (idx|bf16 weight) + drug -> {start,len} lists.
    k_prep<<<(E + 255) / 256, 256, 0, stream>>>(group_ids, prot_idx, psexp,
                                                g2d, gcnt, gl2, pw, E);

    // Drug-major fused pooling: ND*CH waves, 4 waves per block.
    k_fused_drug<<<(ND * CH) / 4, 256, 0, stream>>>(phb, pw, gl2, gcnt, dsum);

    // Fingerprint + out_proj + ReLU.
    k4_out<<<ND, H, 0, stream>>>(dsum, gcnt, w_out, b_out, (float*)d_out);
}